// Round 1
// baseline (334.481 us; speedup 1.0000x reference)
//
#include <hip/hip_runtime.h>
#include <math.h>

#define BATCH 8
#define CH 64
#define NHEADS 8
#define NPIX 4096
#define NROW 1536

// ---------------- reductions ----------------
__device__ inline float wave_max(float v) {
#pragma unroll
    for (int off = 32; off; off >>= 1) v = fmaxf(v, __shfl_down(v, off, 64));
    return v;
}
__device__ inline float wave_sum(float v) {
#pragma unroll
    for (int off = 32; off; off >>= 1) v += __shfl_down(v, off, 64);
    return v;
}

// ---------------- 1) GroupNorm stats -> per-(b,c) scale/shift ----------------
// grid 256 = (b*32+g), block 256. group g covers channels {2g, 2g+1}, 8192 elems.
__global__ __launch_bounds__(256) void gn_stats_kernel(
    const float* __restrict__ x, const float* __restrict__ gamma,
    const float* __restrict__ beta, float* __restrict__ scale, float* __restrict__ shift) {
    int b = blockIdx.x >> 5, g = blockIdx.x & 31;
    const float4* p = (const float4*)(x + ((size_t)b * CH + 2 * g) * NPIX);
    float s = 0.f, ss = 0.f;
#pragma unroll
    for (int i = 0; i < 8; ++i) {
        float4 v = p[threadIdx.x + i * 256];
        s += v.x + v.y + v.z + v.w;
        ss += v.x * v.x + v.y * v.y + v.z * v.z + v.w * v.w;
    }
    s = wave_sum(s);
    ss = wave_sum(ss);
    __shared__ float rs[4], rss[4];
    int lane = threadIdx.x & 63, wv = threadIdx.x >> 6;
    if (lane == 0) { rs[wv] = s; rss[wv] = ss; }
    __syncthreads();
    if (threadIdx.x == 0) {
        s = rs[0] + rs[1] + rs[2] + rs[3];
        ss = rss[0] + rss[1] + rss[2] + rss[3];
        float mu = s * (1.f / 8192.f);
        float var = ss * (1.f / 8192.f) - mu * mu;
        float rstd = rsqrtf(var + 1e-6f);
#pragma unroll
        for (int cc = 0; cc < 2; ++cc) {
            int c = 2 * g + cc;
            float sc = rstd * gamma[c];
            scale[b * CH + c] = sc;
            shift[b * CH + c] = beta[c] - mu * sc;
        }
    }
}

// ---------------- 2) GEMM1: qkv[b,row,pix] = W[row,:] @ xn[b,:,pix] + bias ----------------
// norm fused into B-load. grid (32 pixtiles, 12 rowtiles, 8 b), 128x128 tile, K=64.
__global__ __launch_bounds__(256) void gemm1_kernel(
    const float* __restrict__ x, const float* __restrict__ scale_all,
    const float* __restrict__ shift_all,
    const float* __restrict__ Wq, const float* __restrict__ bq,
    const float* __restrict__ Wk, const float* __restrict__ bk,
    const float* __restrict__ Wv, const float* __restrict__ bv,
    float* __restrict__ qkv) {
    __shared__ float As[64][132];  // As[k][r]  (W transposed)
    __shared__ float Bs[64][132];  // Bs[k][pix]
    int b = blockIdx.z;
    int row0 = blockIdx.y * 128, pix0 = blockIdx.x * 128;
    const float* W; const float* bias; int wr0;
    if (row0 < 512)       { W = Wq; bias = bq; wr0 = row0; }
    else if (row0 < 1024) { W = Wk; bias = bk; wr0 = row0 - 512; }
    else                  { W = Wv; bias = bv; wr0 = row0 - 1024; }
    const float* scale = scale_all + b * CH;
    const float* shift = shift_all + b * CH;
#pragma unroll
    for (int i = 0; i < 8; ++i) {
        int idx4 = threadIdx.x + i * 256;
        int r = idx4 >> 4, c4 = idx4 & 15;
        float4 w4 = ((const float4*)(W + (size_t)(wr0 + r) * 64))[c4];
        int k = c4 * 4;
        As[k][r] = w4.x; As[k + 1][r] = w4.y; As[k + 2][r] = w4.z; As[k + 3][r] = w4.w;
    }
#pragma unroll
    for (int i = 0; i < 8; ++i) {
        int idx4 = threadIdx.x + i * 256;
        int k = idx4 >> 5, p4 = (idx4 & 31) * 4;
        float4 v = *(const float4*)(x + ((size_t)b * CH + k) * NPIX + pix0 + p4);
        float sc = scale[k], sh = shift[k];
        v.x = v.x * sc + sh; v.y = v.y * sc + sh; v.z = v.z * sc + sh; v.w = v.w * sc + sh;
        *(float4*)&Bs[k][p4] = v;
    }
    __syncthreads();
    int ty = threadIdx.x >> 4, tx = threadIdx.x & 15;
    float acc[8][8];
#pragma unroll
    for (int i = 0; i < 8; ++i)
#pragma unroll
        for (int j = 0; j < 8; ++j) acc[i][j] = 0.f;
    for (int k = 0; k < 64; ++k) {
        float a[8], bb[8];
        *(float4*)&a[0] = *(const float4*)&As[k][ty * 8];
        *(float4*)&a[4] = *(const float4*)&As[k][ty * 8 + 4];
        *(float4*)&bb[0] = *(const float4*)&Bs[k][tx * 8];
        *(float4*)&bb[4] = *(const float4*)&Bs[k][tx * 8 + 4];
#pragma unroll
        for (int i = 0; i < 8; ++i)
#pragma unroll
            for (int j = 0; j < 8; ++j) acc[i][j] += a[i] * bb[j];
    }
#pragma unroll
    for (int i = 0; i < 8; ++i) {
        int r = row0 + ty * 8 + i;
        float bi = bias[wr0 + ty * 8 + i];
        float* o = qkv + ((size_t)b * NROW + r) * NPIX + pix0 + tx * 8;
        float4 o0 = {acc[i][0] + bi, acc[i][1] + bi, acc[i][2] + bi, acc[i][3] + bi};
        float4 o1 = {acc[i][4] + bi, acc[i][5] + bi, acc[i][6] + bi, acc[i][7] + bi};
        *(float4*)o = o0;
        *(float4*)(o + 4) = o1;
    }
}

// ---------------- 3) row softmax stats (max, sumexp) for q rows (0..511) and k rows (512..1023) ----
// grid 8192 = (b*1024+row), block 256, stats[b][row][2]
__global__ __launch_bounds__(256) void rowstats_kernel(
    const float* __restrict__ qkv, float* __restrict__ stats) {
    int b = blockIdx.x >> 10, row = blockIdx.x & 1023;
    const float4* p = (const float4*)(qkv + ((size_t)b * NROW + row) * NPIX);
    float4 v[4];
    float m = -3.0e38f;
#pragma unroll
    for (int i = 0; i < 4; ++i) {
        v[i] = p[threadIdx.x + i * 256];
        m = fmaxf(m, fmaxf(fmaxf(v[i].x, v[i].y), fmaxf(v[i].z, v[i].w)));
    }
    m = wave_max(m);
    __shared__ float rm[4], rsum[4];
    int lane = threadIdx.x & 63, wv = threadIdx.x >> 6;
    if (lane == 0) rm[wv] = m;
    __syncthreads();
    m = fmaxf(fmaxf(rm[0], rm[1]), fmaxf(rm[2], rm[3]));
    float se = 0.f;
#pragma unroll
    for (int i = 0; i < 4; ++i)
        se += expf(v[i].x - m) + expf(v[i].y - m) + expf(v[i].z - m) + expf(v[i].w - m);
    se = wave_sum(se);
    if (lane == 0) rsum[wv] = se;
    __syncthreads();
    if (threadIdx.x == 0) {
        float* st = stats + (b * 1024 + row) * 2;
        st[0] = m;
        st[1] = rsum[0] + rsum[1] + rsum[2] + rsum[3];
    }
}

// ---------------- 4) zero s_raw ----------------
__global__ void zero_sraw(float* __restrict__ sraw) {
    ((float4*)sraw)[blockIdx.x * 256 + threadIdx.x] = make_float4(0.f, 0.f, 0.f, 0.f);
}

// ---------------- 5) s_raw[b,h,p,c] += sum_pix exp(k[p,pix]-kmax[p]) * v[c,pix] ----------------
// grid (4 chunks, 8 h, 8 b). thread owns 2 p x 8 c.
__global__ __launch_bounds__(256) void s_accum_kernel(
    const float* __restrict__ qkv, const float* __restrict__ stats, float* __restrict__ sraw) {
    int ch = blockIdx.x, h = blockIdx.y, b = blockIdx.z;
    __shared__ float E[64][68];   // exp(k - kmax)  [p][pix]
    __shared__ float Vt[64][68];  // v transposed   [pix][c]
    __shared__ float kmx[64];
    if (threadIdx.x < 64)
        kmx[threadIdx.x] = stats[(b * 1024 + 512 + h * 64 + threadIdx.x) * 2];
    int p2 = threadIdx.x >> 3;          // 0..31  -> rows 2*p2, 2*p2+1
    int c0 = (threadIdx.x & 7) * 8;     // 8 c per thread
    float acc[2][8];
#pragma unroll
    for (int i = 0; i < 2; ++i)
#pragma unroll
        for (int j = 0; j < 8; ++j) acc[i][j] = 0.f;
    for (int t = 0; t < 16; ++t) {
        int px = ch * 1024 + t * 64;
        __syncthreads();
#pragma unroll
        for (int i = 0; i < 4; ++i) {
            int idx4 = threadIdx.x + i * 256;
            int r = idx4 >> 4, q4 = (idx4 & 15) * 4;
            float4 kv = *(const float4*)(qkv + ((size_t)b * NROW + 512 + h * 64 + r) * NPIX + px + q4);
            float rm = kmx[r];
            E[r][q4 + 0] = expf(kv.x - rm);
            E[r][q4 + 1] = expf(kv.y - rm);
            E[r][q4 + 2] = expf(kv.z - rm);
            E[r][q4 + 3] = expf(kv.w - rm);
            float4 vv = *(const float4*)(qkv + ((size_t)b * NROW + 1024 + h * 64 + r) * NPIX + px + q4);
            Vt[q4 + 0][r] = vv.x; Vt[q4 + 1][r] = vv.y; Vt[q4 + 2][r] = vv.z; Vt[q4 + 3][r] = vv.w;
        }
        __syncthreads();
#pragma unroll 4
        for (int j = 0; j < 64; ++j) {
            float e0 = E[p2 * 2][j], e1 = E[p2 * 2 + 1][j];
            float4 va = *(const float4*)&Vt[j][c0];
            float4 vb = *(const float4*)&Vt[j][c0 + 4];
            acc[0][0] += e0 * va.x; acc[0][1] += e0 * va.y; acc[0][2] += e0 * va.z; acc[0][3] += e0 * va.w;
            acc[0][4] += e0 * vb.x; acc[0][5] += e0 * vb.y; acc[0][6] += e0 * vb.z; acc[0][7] += e0 * vb.w;
            acc[1][0] += e1 * va.x; acc[1][1] += e1 * va.y; acc[1][2] += e1 * va.z; acc[1][3] += e1 * va.w;
            acc[1][4] += e1 * vb.x; acc[1][5] += e1 * vb.y; acc[1][6] += e1 * vb.z; acc[1][7] += e1 * vb.w;
        }
    }
    float* srow = sraw + (((size_t)b * 8 + h) * 64) * 64;
#pragma unroll
    for (int pp = 0; pp < 2; ++pp)
#pragma unroll
        for (int j = 0; j < 8; ++j)
            atomicAdd(&srow[(p2 * 2 + pp) * 64 + c0 + j], acc[pp][j]);
}

// ---------------- 6) T[b,o,hp] = (Wo[o, h*64:..] . s[b,h,p,:]) / (8*ksum*qsum) ----------------
__global__ __launch_bounds__(256) void t_kernel(
    const float* __restrict__ sraw, const float* __restrict__ stats,
    const float* __restrict__ Wo, float* __restrict__ T) {
    int idx = blockIdx.x * 256 + threadIdx.x;
    int hp = idx & 511, o = (idx >> 9) & 63, b = idx >> 15;
    int h = hp >> 6, pp = hp & 63;
    const float* srow = sraw + (((size_t)b * 8 + h) * 64 + pp) * 64;
    const float* wrow = Wo + (size_t)o * 512 + h * 64;
    float acc = 0.f;
#pragma unroll
    for (int c = 0; c < 64; ++c) acc += wrow[c] * srow[c];
    float ksum = stats[(b * 1024 + 512 + hp) * 2 + 1];
    float qsum = stats[(b * 1024 + hp) * 2 + 1];
    T[idx] = acc / (8.f * ksum * qsum);
}

// ---------------- 7) GEMM2: out[b,o,pix] = bo[o] + sum_hp T[b,o,hp]*exp(q[hp,pix]-qmax[hp]) ----
// grid (32 pixtiles, 8 b). out tile 64 x 128.
__global__ __launch_bounds__(256) void gemm2_kernel(
    const float* __restrict__ qkv, const float* __restrict__ stats_all,
    const float* __restrict__ T_all, const float* __restrict__ bo, float* __restrict__ out) {
    int b = blockIdx.y, pix0 = blockIdx.x * 128;
    __shared__ float Ts[64][68];   // Ts[hp_local][o]
    __shared__ float Es[64][132];  // Es[hp_local][pix]
    int ty = threadIdx.x >> 4, tx = threadIdx.x & 15;
    const float* T = T_all + (size_t)b * 64 * 512;
    const float* stats = stats_all + b * 1024 * 2;
    float acc[4][8];
#pragma unroll
    for (int i = 0; i < 4; ++i)
#pragma unroll
        for (int j = 0; j < 8; ++j) acc[i][j] = 0.f;
    for (int hc = 0; hc < 8; ++hc) {
        int hp0 = hc * 64;
        __syncthreads();
#pragma unroll
        for (int i = 0; i < 4; ++i) {
            int idx4 = threadIdx.x + i * 256;
            int o = idx4 >> 4, l4 = (idx4 & 15) * 4;
            float4 t4 = *(const float4*)(T + (size_t)o * 512 + hp0 + l4);
            Ts[l4 + 0][o] = t4.x; Ts[l4 + 1][o] = t4.y; Ts[l4 + 2][o] = t4.z; Ts[l4 + 3][o] = t4.w;
        }
#pragma unroll
        for (int i = 0; i < 8; ++i) {
            int idx4 = threadIdx.x + i * 256;
            int l = idx4 >> 5, p4 = (idx4 & 31) * 4;
            int row = hp0 + l;
            float mx = stats[row * 2];
            float4 qv = *(const float4*)(qkv + ((size_t)b * NROW + row) * NPIX + pix0 + p4);
            Es[l][p4 + 0] = expf(qv.x - mx);
            Es[l][p4 + 1] = expf(qv.y - mx);
            Es[l][p4 + 2] = expf(qv.z - mx);
            Es[l][p4 + 3] = expf(qv.w - mx);
        }
        __syncthreads();
        for (int l = 0; l < 64; ++l) {
            float a[4], bb[8];
            *(float4*)&a[0] = *(const float4*)&Ts[l][ty * 4];
            *(float4*)&bb[0] = *(const float4*)&Es[l][tx * 8];
            *(float4*)&bb[4] = *(const float4*)&Es[l][tx * 8 + 4];
#pragma unroll
            for (int i = 0; i < 4; ++i)
#pragma unroll
                for (int j = 0; j < 8; ++j) acc[i][j] += a[i] * bb[j];
        }
    }
#pragma unroll
    for (int i = 0; i < 4; ++i) {
        int o = ty * 4 + i;
        float bi = bo[o];
        float* op = out + ((size_t)b * 64 + o) * NPIX + pix0 + tx * 8;
        float4 o0 = {acc[i][0] + bi, acc[i][1] + bi, acc[i][2] + bi, acc[i][3] + bi};
        float4 o1 = {acc[i][4] + bi, acc[i][5] + bi, acc[i][6] + bi, acc[i][7] + bi};
        *(float4*)op = o0;
        *(float4*)(op + 4) = o1;
    }
}

// ---------------- workspace layout (floats) ----------------
#define OFF_SCALE 0                     // [8][64]            = 512
#define OFF_SHIFT 512                   // [8][64]            = 512
#define OFF_STATS 1024                  // [8][1024][2]       = 16384
#define OFF_SRAW  32768                 // [8][8][64][64]     = 262144
#define OFF_T     294912                // [8][64][512]       = 262144
#define OFF_QKV   557056                // [8][1536][4096]    = 50331648
#define WS_FLOATS (557056 + 50331648)

extern "C" void kernel_launch(void* const* d_in, const int* in_sizes, int n_in,
                              void* d_out, int out_size, void* d_ws, size_t ws_size,
                              hipStream_t stream) {
    const float* x  = (const float*)d_in[0];
    const float* gg = (const float*)d_in[1];
    const float* gb = (const float*)d_in[2];
    const float* Wq = (const float*)d_in[3];
    const float* bq = (const float*)d_in[4];
    const float* Wk = (const float*)d_in[5];
    const float* bk = (const float*)d_in[6];
    const float* Wv = (const float*)d_in[7];
    const float* bv = (const float*)d_in[8];
    const float* Wo = (const float*)d_in[9];
    const float* bo = (const float*)d_in[10];
    float* out = (float*)d_out;
    float* ws = (float*)d_ws;
    if (ws_size < (size_t)WS_FLOATS * sizeof(float)) return;  // insufficient scratch -> will fail validation (signals ws issue)

    float* scale = ws + OFF_SCALE;
    float* shift = ws + OFF_SHIFT;
    float* stats = ws + OFF_STATS;
    float* sraw  = ws + OFF_SRAW;
    float* T     = ws + OFF_T;
    float* qkv   = ws + OFF_QKV;

    gn_stats_kernel<<<256, 256, 0, stream>>>(x, gg, gb, scale, shift);
    gemm1_kernel<<<dim3(32, 12, 8), 256, 0, stream>>>(x, scale, shift, Wq, bq, Wk, bk, Wv, bv, qkv);
    rowstats_kernel<<<8192, 256, 0, stream>>>(qkv, stats);
    zero_sraw<<<256, 256, 0, stream>>>(sraw);
    s_accum_kernel<<<dim3(4, 8, 8), 256, 0, stream>>>(qkv, stats, sraw);
    t_kernel<<<1024, 256, 0, stream>>>(sraw, stats, Wo, T);
    gemm2_kernel<<<dim3(32, 8), 256, 0, stream>>>(qkv, stats, T, bo, out);
}

// Round 3
// 326.180 us; speedup vs baseline: 1.0254x; 1.0254x over previous
//
#include <hip/hip_runtime.h>
#include <math.h>

#define BATCH 8
#define CH 64
#define NHEADS 8
#define NPIX 4096
#define NROW 1536

// ---------------- reductions ----------------
__device__ inline float wave_sum(float v) {
#pragma unroll
    for (int off = 32; off; off >>= 1) v += __shfl_down(v, off, 64);
    return v;
}

// ---------------- 1) GroupNorm stats -> per-(b,c) scale/shift; blocks >=256 zero accum ws ----
// grid 520 = 256 gn blocks (b*32+g) + 264 zero blocks (264*256 float4 = 270336 floats).
__global__ __launch_bounds__(256) void gn_zero_kernel(
    const float* __restrict__ x, const float* __restrict__ gamma,
    const float* __restrict__ beta, float* __restrict__ scale, float* __restrict__ shift,
    float* __restrict__ zbase) {
    if (blockIdx.x >= 256) {
        ((float4*)zbase)[(blockIdx.x - 256) * 256 + threadIdx.x] =
            make_float4(0.f, 0.f, 0.f, 0.f);
        return;
    }
    int b = blockIdx.x >> 5, g = blockIdx.x & 31;
    const float4* p = (const float4*)(x + ((size_t)b * CH + 2 * g) * NPIX);
    float s = 0.f, ss = 0.f;
#pragma unroll
    for (int i = 0; i < 8; ++i) {
        float4 v = p[threadIdx.x + i * 256];
        s += v.x + v.y + v.z + v.w;
        ss += v.x * v.x + v.y * v.y + v.z * v.z + v.w * v.w;
    }
    s = wave_sum(s);
    ss = wave_sum(ss);
    __shared__ float rs[4], rss[4];
    int lane = threadIdx.x & 63, wv = threadIdx.x >> 6;
    if (lane == 0) { rs[wv] = s; rss[wv] = ss; }
    __syncthreads();
    if (threadIdx.x == 0) {
        s = rs[0] + rs[1] + rs[2] + rs[3];
        ss = rss[0] + rss[1] + rss[2] + rss[3];
        float mu = s * (1.f / 8192.f);
        float var = ss * (1.f / 8192.f) - mu * mu;
        float rstd = rsqrtf(var + 1e-6f);
#pragma unroll
        for (int cc = 0; cc < 2; ++cc) {
            int c = 2 * g + cc;
            float sc = rstd * gamma[c];
            scale[b * CH + c] = sc;
            shift[b * CH + c] = beta[c] - mu * sc;
        }
    }
}

// ---------------- 2) GEMM1: qkv rows = W @ xn + bias; exp fused for q,k rows; rowsums atomic ----
// grid (32 pixtiles, 12 rowtiles, 8 b), 128x128 tile, K=64.
// Bs XOR swizzle on float4 slot: js = j ^ (j>>3). For the inner-loop read set
// j = 2*tx(+1), slot mod 8 = (t1, t0^t3, t2)(^1) -> every bank quad hit exactly
// twice across 16 lanes = free 2-way. (Round-2's <<1 variant left bit0 fixed ->
// still 4-way, same as the measured 1.18e7-conflict baseline.)
__global__ __launch_bounds__(256) void gemm1_kernel(
    const float* __restrict__ x, const float* __restrict__ scale_all,
    const float* __restrict__ shift_all,
    const float* __restrict__ Wq, const float* __restrict__ bq,
    const float* __restrict__ Wk, const float* __restrict__ bk,
    const float* __restrict__ Wv, const float* __restrict__ bv,
    float* __restrict__ qkv, float* __restrict__ qsum, float* __restrict__ ksum) {
    __shared__ float As[64][132];  // As[k][r]  (W transposed)
    __shared__ float Bs[64][132];  // Bs[k][swizzled px]
    int b = blockIdx.z;
    int row0 = blockIdx.y * 128, pix0 = blockIdx.x * 128;
    int mode = row0 >> 9;                 // 0=q, 1=k, 2=v
    int wr0 = row0 - (mode << 9);
    const float* W; const float* bias;
    if (mode == 0)      { W = Wq; bias = bq; }
    else if (mode == 1) { W = Wk; bias = bk; }
    else                { W = Wv; bias = bv; }
    const float* scale = scale_all + b * CH;
    const float* shift = shift_all + b * CH;
#pragma unroll
    for (int i = 0; i < 8; ++i) {
        int idx4 = threadIdx.x + i * 256;
        int r = idx4 >> 4, c4 = idx4 & 15;
        float4 w4 = ((const float4*)(W + (size_t)(wr0 + r) * 64))[c4];
        int k = c4 * 4;
        As[k][r] = w4.x; As[k + 1][r] = w4.y; As[k + 2][r] = w4.z; As[k + 3][r] = w4.w;
    }
#pragma unroll
    for (int i = 0; i < 8; ++i) {
        int idx4 = threadIdx.x + i * 256;
        int k = idx4 >> 5, j = idx4 & 31;
        float4 v = *(const float4*)(x + ((size_t)b * CH + k) * NPIX + pix0 + j * 4);
        float sc = scale[k], sh = shift[k];
        v.x = v.x * sc + sh; v.y = v.y * sc + sh; v.z = v.z * sc + sh; v.w = v.w * sc + sh;
        int js = j ^ (j >> 3);
        *(float4*)&Bs[k][js * 4] = v;
    }
    __syncthreads();
    int ty = threadIdx.x >> 4, tx = threadIdx.x & 15;
    int j0 = tx * 2, j1 = tx * 2 + 1;
    int cs0 = (j0 ^ (j0 >> 3)) * 4;
    int cs1 = (j1 ^ (j1 >> 3)) * 4;
    float acc[8][8];
#pragma unroll
    for (int i = 0; i < 8; ++i)
#pragma unroll
        for (int j = 0; j < 8; ++j) acc[i][j] = 0.f;
    for (int k = 0; k < 64; ++k) {
        float a[8], bb[8];
        *(float4*)&a[0] = *(const float4*)&As[k][ty * 8];
        *(float4*)&a[4] = *(const float4*)&As[k][ty * 8 + 4];
        *(float4*)&bb[0] = *(const float4*)&Bs[k][cs0];
        *(float4*)&bb[4] = *(const float4*)&Bs[k][cs1];
#pragma unroll
        for (int i = 0; i < 8; ++i)
#pragma unroll
            for (int j = 0; j < 8; ++j) acc[i][j] += a[i] * bb[j];
    }
    if (mode < 2) {
        float* rs = (mode == 0 ? qsum : ksum) + b * 512;
#pragma unroll
        for (int i = 0; i < 8; ++i) {
            int rl = wr0 + ty * 8 + i;
            float bi = bias[rl];
            float e[8];
            float sum = 0.f;
#pragma unroll
            for (int j = 0; j < 8; ++j) { e[j] = __expf(acc[i][j] + bi); sum += e[j]; }
            float* o = qkv + ((size_t)b * NROW + row0 + ty * 8 + i) * NPIX + pix0 + tx * 8;
            *(float4*)o = make_float4(e[0], e[1], e[2], e[3]);
            *(float4*)(o + 4) = make_float4(e[4], e[5], e[6], e[7]);
            sum += __shfl_xor(sum, 1, 16);
            sum += __shfl_xor(sum, 2, 16);
            sum += __shfl_xor(sum, 4, 16);
            sum += __shfl_xor(sum, 8, 16);
            if (tx == 0) atomicAdd(&rs[rl], sum);
        }
    } else {
#pragma unroll
        for (int i = 0; i < 8; ++i) {
            float bi = bias[wr0 + ty * 8 + i];
            float* o = qkv + ((size_t)b * NROW + row0 + ty * 8 + i) * NPIX + pix0 + tx * 8;
            *(float4*)o = make_float4(acc[i][0] + bi, acc[i][1] + bi, acc[i][2] + bi, acc[i][3] + bi);
            *(float4*)(o + 4) = make_float4(acc[i][4] + bi, acc[i][5] + bi, acc[i][6] + bi, acc[i][7] + bi);
        }
    }
}

// ---------------- 3) s_raw[b,h,p,c] += sum_px expk[p,px] * v[c,px] ----------------
// grid (8 chunks, 8 h, 8 b). thread owns 2 p x 8 c. Pure FMA inner loop (exp precomputed).
__global__ __launch_bounds__(256) void s_accum_kernel(
    const float* __restrict__ qkv, float* __restrict__ sraw) {
    int ch = blockIdx.x, h = blockIdx.y, b = blockIdx.z;
    __shared__ float E[64][68];   // expk [p][px]
    __shared__ float Vt[64][68];  // v transposed [px][c]
    int p2 = threadIdx.x >> 3;
    int c0 = (threadIdx.x & 7) * 8;
    float acc[2][8];
#pragma unroll
    for (int i = 0; i < 2; ++i)
#pragma unroll
        for (int j = 0; j < 8; ++j) acc[i][j] = 0.f;
    for (int t = 0; t < 8; ++t) {
        int px = ch * 512 + t * 64;
        __syncthreads();
#pragma unroll
        for (int i = 0; i < 4; ++i) {
            int idx4 = threadIdx.x + i * 256;
            int r = idx4 >> 4, q4 = (idx4 & 15) * 4;
            float4 kv = *(const float4*)(qkv + ((size_t)b * NROW + 512 + h * 64 + r) * NPIX + px + q4);
            *(float4*)&E[r][q4] = kv;
            float4 vv = *(const float4*)(qkv + ((size_t)b * NROW + 1024 + h * 64 + r) * NPIX + px + q4);
            Vt[q4 + 0][r] = vv.x; Vt[q4 + 1][r] = vv.y; Vt[q4 + 2][r] = vv.z; Vt[q4 + 3][r] = vv.w;
        }
        __syncthreads();
#pragma unroll 4
        for (int j = 0; j < 64; ++j) {
            float e0 = E[p2 * 2][j], e1 = E[p2 * 2 + 1][j];
            float4 va = *(const float4*)&Vt[j][c0];
            float4 vb = *(const float4*)&Vt[j][c0 + 4];
            acc[0][0] += e0 * va.x; acc[0][1] += e0 * va.y; acc[0][2] += e0 * va.z; acc[0][3] += e0 * va.w;
            acc[0][4] += e0 * vb.x; acc[0][5] += e0 * vb.y; acc[0][6] += e0 * vb.z; acc[0][7] += e0 * vb.w;
            acc[1][0] += e1 * va.x; acc[1][1] += e1 * va.y; acc[1][2] += e1 * va.z; acc[1][3] += e1 * va.w;
            acc[1][4] += e1 * vb.x; acc[1][5] += e1 * vb.y; acc[1][6] += e1 * vb.z; acc[1][7] += e1 * vb.w;
        }
    }
    float* srow = sraw + (((size_t)b * 8 + h) * 64) * 64;
#pragma unroll
    for (int pp = 0; pp < 2; ++pp)
#pragma unroll
        for (int j = 0; j < 8; ++j)
            atomicAdd(&srow[(p2 * 2 + pp) * 64 + c0 + j], acc[pp][j]);
}

// ---------------- 4) T[b,o,hp] = (Wo[o,h*64:] . sraw[b,h,p,:]) / (8*ksum*qsum) ----------------
__global__ __launch_bounds__(256) void t_kernel(
    const float* __restrict__ sraw, const float* __restrict__ qsum_all,
    const float* __restrict__ ksum_all, const float* __restrict__ Wo, float* __restrict__ T) {
    int idx = blockIdx.x * 256 + threadIdx.x;
    int hp = idx & 511, o = (idx >> 9) & 63, b = idx >> 15;
    int h = hp >> 6, pp = hp & 63;
    const float* srow = sraw + (((size_t)b * 8 + h) * 64 + pp) * 64;
    const float* wrow = Wo + (size_t)o * 512 + h * 64;
    float acc = 0.f;
#pragma unroll
    for (int c = 0; c < 64; ++c) acc += wrow[c] * srow[c];
    float ks = ksum_all[b * 512 + hp];
    float qs = qsum_all[b * 512 + hp];
    T[idx] = acc / (8.f * ks * qs);
}

// ---------------- 5) GEMM2: out[b,o,pix] = bo[o] + sum_hp T[b,o,hp]*expq[b,hp,pix] ----------
// grid (64 pixtiles, 8 b). out tile 64 o x 64 px. thread: 2 o x 8 px.
__global__ __launch_bounds__(256) void gemm2_kernel(
    const float* __restrict__ qkv, const float* __restrict__ T_all,
    const float* __restrict__ bo, float* __restrict__ out) {
    int b = blockIdx.y, pix0 = blockIdx.x * 64;
    __shared__ float Ts[64][66];   // Ts[hp_local][o]
    __shared__ float Es[64][68];   // Es[hp_local][px]
    int ty = threadIdx.x >> 3, tx = threadIdx.x & 7;
    const float* T = T_all + (size_t)b * 64 * 512;
    float acc[2][8];
#pragma unroll
    for (int i = 0; i < 2; ++i)
#pragma unroll
        for (int j = 0; j < 8; ++j) acc[i][j] = 0.f;
    for (int hc = 0; hc < 8; ++hc) {
        int hp0 = hc * 64;
        __syncthreads();
#pragma unroll
        for (int i = 0; i < 4; ++i) {
            int idx4 = threadIdx.x + i * 256;
            int o = idx4 >> 4, l4 = (idx4 & 15) * 4;
            float4 t4 = *(const float4*)(T + (size_t)o * 512 + hp0 + l4);
            Ts[l4 + 0][o] = t4.x; Ts[l4 + 1][o] = t4.y; Ts[l4 + 2][o] = t4.z; Ts[l4 + 3][o] = t4.w;
        }
#pragma unroll
        for (int i = 0; i < 4; ++i) {
            int idx4 = threadIdx.x + i * 256;
            int l = idx4 >> 4, p4 = (idx4 & 15) * 4;
            float4 qv = *(const float4*)(qkv + ((size_t)b * NROW + hp0 + l) * NPIX + pix0 + p4);
            *(float4*)&Es[l][p4] = qv;
        }
        __syncthreads();
        for (int l = 0; l < 64; ++l) {
            float2 a = *(const float2*)&Ts[l][ty * 2];
            float bb[8];
            *(float4*)&bb[0] = *(const float4*)&Es[l][tx * 8];
            *(float4*)&bb[4] = *(const float4*)&Es[l][tx * 8 + 4];
#pragma unroll
            for (int j = 0; j < 8; ++j) {
                acc[0][j] += a.x * bb[j];
                acc[1][j] += a.y * bb[j];
            }
        }
    }
#pragma unroll
    for (int i = 0; i < 2; ++i) {
        int o = ty * 2 + i;
        float bi = bo[o];
        float* op = out + ((size_t)b * 64 + o) * NPIX + pix0 + tx * 8;
        *(float4*)op = make_float4(acc[i][0] + bi, acc[i][1] + bi, acc[i][2] + bi, acc[i][3] + bi);
        *(float4*)(op + 4) = make_float4(acc[i][4] + bi, acc[i][5] + bi, acc[i][6] + bi, acc[i][7] + bi);
    }
}

// ---------------- workspace layout (floats) ----------------
#define OFF_SCALE 0                     // [8][64]          = 512
#define OFF_SHIFT 512                   // [8][64]          = 512
#define OFF_QSUM  1024                  // [8][512]         = 4096
#define OFF_KSUM  5120                  // [8][512]         = 4096
#define OFF_SRAW  9216                  // [8][8][64][64]   = 262144
#define OFF_T     271360                // [8][64][512]     = 262144
#define OFF_QKV   533504                // [8][1536][4096]  = 50331648
#define WS_FLOATS (533504 + 50331648)
// zero region: [OFF_QSUM, OFF_SRAW + 262144) = 270336 floats = 67584 float4 = 264 blocks * 256

extern "C" void kernel_launch(void* const* d_in, const int* in_sizes, int n_in,
                              void* d_out, int out_size, void* d_ws, size_t ws_size,
                              hipStream_t stream) {
    const float* x  = (const float*)d_in[0];
    const float* gg = (const float*)d_in[1];
    const float* gb = (const float*)d_in[2];
    const float* Wq = (const float*)d_in[3];
    const float* bq = (const float*)d_in[4];
    const float* Wk = (const float*)d_in[5];
    const float* bk = (const float*)d_in[6];
    const float* Wv = (const float*)d_in[7];
    const float* bv = (const float*)d_in[8];
    const float* Wo = (const float*)d_in[9];
    const float* bo = (const float*)d_in[10];
    float* out = (float*)d_out;
    float* ws = (float*)d_ws;
    if (ws_size < (size_t)WS_FLOATS * sizeof(float)) return;

    float* scale = ws + OFF_SCALE;
    float* shift = ws + OFF_SHIFT;
    float* qsum  = ws + OFF_QSUM;
    float* ksum  = ws + OFF_KSUM;
    float* sraw  = ws + OFF_SRAW;
    float* T     = ws + OFF_T;
    float* qkv   = ws + OFF_QKV;

    gn_zero_kernel<<<520, 256, 0, stream>>>(x, gg, gb, scale, shift, ws + OFF_QSUM);
    gemm1_kernel<<<dim3(32, 12, 8), 256, 0, stream>>>(x, scale, shift, Wq, bq, Wk, bk, Wv, bv,
                                                      qkv, qsum, ksum);
    s_accum_kernel<<<dim3(8, 8, 8), 256, 0, stream>>>(qkv, sraw);
    t_kernel<<<1024, 256, 0, stream>>>(sraw, qsum, ksum, Wo, T);
    gemm2_kernel<<<dim3(64, 8), 256, 0, stream>>>(qkv, T, bo, out);
}

// Round 7
// 193.953 us; speedup vs baseline: 1.7245x; 1.6817x over previous
//
#include <hip/hip_runtime.h>
#include <math.h>

#define BATCH 8
#define CH 64
#define NHEADS 8
#define NPIX 4096
#define NROW 1536

typedef __attribute__((ext_vector_type(8))) short short8v;
typedef __attribute__((ext_vector_type(16))) float f32x16;

// ---------------- reductions ----------------
__device__ inline float wave_sum(float v) {
#pragma unroll
    for (int off = 32; off; off >>= 1) v += __shfl_down(v, off, 64);
    return v;
}

// rne fp32 -> bf16 hi, and lo = bf16(f - hi)
__device__ inline void split_bf16(float f, short& h, short& l) {
    unsigned u = __float_as_uint(f);
    unsigned r = u + 0x7FFFu + ((u >> 16) & 1u);
    h = (short)(r >> 16);
    float hf = __uint_as_float(r & 0xFFFF0000u);
    float lf = f - hf;
    unsigned u2 = __float_as_uint(lf);
    unsigned r2 = u2 + 0x7FFFu + ((u2 >> 16) & 1u);
    l = (short)(r2 >> 16);
}

__device__ inline void split4(const float4 v, uint2& hi, uint2& lo) {
    short h0, h1, h2, h3, l0, l1, l2, l3;
    split_bf16(v.x, h0, l0); split_bf16(v.y, h1, l1);
    split_bf16(v.z, h2, l2); split_bf16(v.w, h3, l3);
    hi.x = (unsigned short)h0 | ((unsigned)(unsigned short)h1 << 16);
    hi.y = (unsigned short)h2 | ((unsigned)(unsigned short)h3 << 16);
    lo.x = (unsigned short)l0 | ((unsigned)(unsigned short)l1 << 16);
    lo.y = (unsigned short)l2 | ((unsigned)(unsigned short)l3 << 16);
}

// ---------------- 1) GroupNorm stats + zero sraw ----------------
// grid 512: blocks <256 do GN (b*32+g); blocks >=256 zero sraw (256*256 f32x4 = 262144 f).
__global__ __launch_bounds__(256) void gn_zero_kernel(
    const float* __restrict__ x, const float* __restrict__ gamma,
    const float* __restrict__ beta, float* __restrict__ scale, float* __restrict__ shift,
    float* __restrict__ zbase) {
    if (blockIdx.x >= 256) {
        ((float4*)zbase)[(blockIdx.x - 256) * 256 + threadIdx.x] =
            make_float4(0.f, 0.f, 0.f, 0.f);
        return;
    }
    int b = blockIdx.x >> 5, g = blockIdx.x & 31;
    const float4* p = (const float4*)(x + ((size_t)b * CH + 2 * g) * NPIX);
    float s = 0.f, ss = 0.f;
#pragma unroll
    for (int i = 0; i < 8; ++i) {
        float4 v = p[threadIdx.x + i * 256];
        s += v.x + v.y + v.z + v.w;
        ss += v.x * v.x + v.y * v.y + v.z * v.z + v.w * v.w;
    }
    s = wave_sum(s);
    ss = wave_sum(ss);
    __shared__ float rs[4], rss[4];
    int lane = threadIdx.x & 63, wv = threadIdx.x >> 6;
    if (lane == 0) { rs[wv] = s; rss[wv] = ss; }
    __syncthreads();
    if (threadIdx.x == 0) {
        s = rs[0] + rs[1] + rs[2] + rs[3];
        ss = rss[0] + rss[1] + rss[2] + rss[3];
        float mu = s * (1.f / 8192.f);
        float var = ss * (1.f / 8192.f) - mu * mu;
        float rstd = rsqrtf(var + 1e-6f);
#pragma unroll
        for (int cc = 0; cc < 2; ++cc) {
            int c = 2 * g + cc;
            float sc = rstd * gamma[c];
            scale[b * CH + c] = sc;
            shift[b * CH + c] = beta[c] - mu * sc;
        }
    }
}

// ---------------- 2) GEMM1 via 3-term split-bf16 MFMA ----------------
// qkv[b,row,pix] = exp?(W[row,:] @ xn[b,:,pix] + bias).
// A = W (M=row), B = xn transposed (N=px), K = 64 fp32 -> virt-K 192 bf16:
//   ks 0-3: Ah*Bh, 4-7: Al*Bh, 8-11: Ah*Bl.
// LDS: As[128r][16 chunks of 8 bf16] 32KB @0, Bs[128px][16 chunks] 32KB @32768.
// chunk' = chunk ^ (row&7). NOTE (R6 audit): k-loop b128 reads span 32 rows ->
// rows r,r+8,r+16,r+24 share bank-quads = 4-way conflict (~1.58x LDS). Known
// next lever: 2x ds_read_b64 with 4-bit granule XOR (s = g ^ (r&15)) -> 2-way free.
// Deliberately not applied before first measurement.
__global__ __launch_bounds__(256) void gemm1_mfma_kernel(
    const float* __restrict__ x, const float* __restrict__ scale_all,
    const float* __restrict__ shift_all,
    const float* __restrict__ Wq, const float* __restrict__ bq,
    const float* __restrict__ Wk, const float* __restrict__ bk,
    const float* __restrict__ Wv, const float* __restrict__ bv,
    float* __restrict__ qkv) {
    __shared__ __align__(16) char lds[65536];
    short* As = (short*)lds;
    short* Bs = (short*)(lds + 32768);
    float* Bf = (float*)lds;

    int t = threadIdx.x;
    int b = blockIdx.z;
    int row0 = blockIdx.y * 128, pix0 = blockIdx.x * 128;
    int mode = blockIdx.y >> 2;          // 0=q, 1=k, 2=v
    int wr0 = (blockIdx.y & 3) * 128;
    const float* W; const float* bias;
    if (mode == 0)      { W = Wq; bias = bq; }
    else if (mode == 1) { W = Wk; bias = bk; }
    else                { W = Wv; bias = bv; }

    // W global loads held in regs (latency hidden under stage1/2)
    float4 w4[8];
#pragma unroll
    for (int i = 0; i < 8; ++i) {
        int idx = t + i * 256;
        int r = idx >> 4, c4 = idx & 15;
        w4[i] = *(const float4*)(W + (size_t)(wr0 + r) * 64 + c4 * 4);
    }

    // stage1: x -> LDS fp32, normalized
    const float* scale = scale_all + b * CH;
    const float* shift = shift_all + b * CH;
#pragma unroll
    for (int i = 0; i < 8; ++i) {
        int idx = t + i * 256;
        int c = idx >> 5, p4 = (idx & 31) * 4;
        float4 v = *(const float4*)(x + ((size_t)b * CH + c) * NPIX + pix0 + p4);
        float sc = scale[c], sh = shift[c];
        v.x = fmaf(v.x, sc, sh); v.y = fmaf(v.y, sc, sh);
        v.z = fmaf(v.z, sc, sh); v.w = fmaf(v.w, sc, sh);
        *(float4*)&Bf[c * 132 + p4] = v;
    }
    __syncthreads();

    // stage2: transposed read into regs (bank-free: consecutive px per lane)
    int mypx = t & 127, chalf = t >> 7;
    float xv[32];
#pragma unroll
    for (int e = 0; e < 32; ++e) xv[e] = Bf[(chalf * 32 + e) * 132 + mypx];
    __syncthreads();

    // stage3a: W -> As bf16 hi/lo
#pragma unroll
    for (int i = 0; i < 8; ++i) {
        int idx = t + i * 256;
        int r = idx >> 4, c4 = (idx & 15) * 4;
        uint2 hi, lo;
        split4(w4[i], hi, lo);
        int chh = ((c4 >> 3) ^ (r & 7));
        int chl = ((8 + (c4 >> 3)) ^ (r & 7));
        *(uint2*)&As[r * 128 + chh * 8 + (c4 & 7)] = hi;
        *(uint2*)&As[r * 128 + chl * 8 + (c4 & 7)] = lo;
    }
    // stage3b: xv -> Bs bf16 hi/lo (overwrites bounce; xv already in regs)
    {
        short h[32], l[32];
#pragma unroll
        for (int e = 0; e < 32; ++e) split_bf16(xv[e], h[e], l[e]);
#pragma unroll
        for (int w = 0; w < 4; ++w) {
            short8v hv, lv;
#pragma unroll
            for (int e = 0; e < 8; ++e) { hv[e] = h[w * 8 + e]; lv[e] = l[w * 8 + e]; }
            int chh = ((chalf * 4 + w) ^ (mypx & 7));
            int chl = ((8 + chalf * 4 + w) ^ (mypx & 7));
            *(short8v*)&Bs[mypx * 128 + chh * 8] = hv;
            *(short8v*)&Bs[mypx * 128 + chl * 8] = lv;
        }
    }
    __syncthreads();

    // k-loop: 12 ksteps, no barriers (whole K resident, read-only)
    int lane = t & 63;
    int wid = t >> 6;
    int wm = wid >> 1, wn = wid & 1;
    int l31 = lane & 31, l7 = lane & 7, kg = lane >> 5;
    int arow = wm * 64 + l31;
    int brow = wn * 64 + l31;
    f32x16 acc[2][2];
#pragma unroll
    for (int mt = 0; mt < 2; ++mt)
#pragma unroll
        for (int nt = 0; nt < 2; ++nt)
#pragma unroll
            for (int e = 0; e < 16; ++e) acc[mt][nt][e] = 0.f;
    const int ACH[12] = {0, 2, 4, 6, 8, 10, 12, 14, 0, 2, 4, 6};
    const int BCH[12] = {0, 2, 4, 6, 0, 2, 4, 6, 8, 10, 12, 14};
#pragma unroll
    for (int ks = 0; ks < 12; ++ks) {
        int ach = ACH[ks] + kg, bch = BCH[ks] + kg;
        short8v a0 = *(const short8v*)&As[arow * 128 + ((ach ^ l7) << 3)];
        short8v a1 = *(const short8v*)&As[(arow + 32) * 128 + ((ach ^ l7) << 3)];
        short8v b0 = *(const short8v*)&Bs[brow * 128 + ((bch ^ l7) << 3)];
        short8v b1 = *(const short8v*)&Bs[(brow + 32) * 128 + ((bch ^ l7) << 3)];
        acc[0][0] = __builtin_amdgcn_mfma_f32_32x32x16_bf16(a0, b0, acc[0][0], 0, 0, 0);
        acc[0][1] = __builtin_amdgcn_mfma_f32_32x32x16_bf16(a0, b1, acc[0][1], 0, 0, 0);
        acc[1][0] = __builtin_amdgcn_mfma_f32_32x32x16_bf16(a1, b0, acc[1][0], 0, 0, 0);
        acc[1][1] = __builtin_amdgcn_mfma_f32_32x32x16_bf16(a1, b1, acc[1][1], 0, 0, 0);
    }

    // epilogue: bias (+exp for q,k), store. D: n(px)=lane&31, m(row)=(j&3)+8*(j>>2)+4*kg
#pragma unroll
    for (int mt = 0; mt < 2; ++mt) {
#pragma unroll
        for (int j = 0; j < 16; ++j) {
            int rl = wm * 64 + mt * 32 + (j & 3) + 8 * (j >> 2) + 4 * kg;
            float bi = bias[wr0 + rl];
#pragma unroll
            for (int nt = 0; nt < 2; ++nt) {
                float val = acc[mt][nt][j] + bi;
                if (mode < 2) val = __expf(val);
                qkv[((size_t)b * NROW + row0 + rl) * NPIX + pix0 + wn * 64 + nt * 32 + l31] = val;
            }
        }
    }
}

// ---------------- 3) row sums of expq (rows 0..511) / expk (512..1023) ----------------
__global__ __launch_bounds__(256) void rowsum_kernel(
    const float* __restrict__ qkv, float* __restrict__ qsum, float* __restrict__ ksum) {
    int b = blockIdx.x >> 10, row = blockIdx.x & 1023;
    const float4* p = (const float4*)(qkv + ((size_t)b * NROW + row) * NPIX);
    float s = 0.f;
#pragma unroll
    for (int i = 0; i < 4; ++i) {
        float4 v = p[threadIdx.x + i * 256];
        s += v.x + v.y + v.z + v.w;
    }
    s = wave_sum(s);
    __shared__ float rs[4];
    int lane = threadIdx.x & 63, wv = threadIdx.x >> 6;
    if (lane == 0) rs[wv] = s;
    __syncthreads();
    if (threadIdx.x == 0) {
        float tot = rs[0] + rs[1] + rs[2] + rs[3];
        if (row < 512) qsum[b * 512 + row] = tot;
        else           ksum[b * 512 + row - 512] = tot;
    }
}

// ---------------- 4) s_accum via MFMA: sraw[b,h,p,c] += sum_px expk[p,px]*v[c,px] ----
// grid (8 kchunks, 8 h, 8 b). Per block: M=64 (p), N=64 (c), K=512 px, split-bf16 3-term.
// LDS per operand: [row 64][half 2][chunk' 8][8 bf16], chunk' = chunk ^ (row&7).
__global__ __launch_bounds__(256) void s_accum_mfma_kernel(
    const float* __restrict__ qkv, float* __restrict__ sraw) {
    __shared__ __align__(16) short lds[16384];  // As(expk) 16KB | Bs(v) 16KB
    short* As = lds;
    short* Bs = lds + 8192;
    int kc = blockIdx.x, h = blockIdx.y, b = blockIdx.z;
    const float* kbase = qkv + ((size_t)b * NROW + 512 + h * 64) * NPIX + kc * 512;
    const float* vbase = qkv + ((size_t)b * NROW + 1024 + h * 64) * NPIX + kc * 512;
    int t = threadIdx.x;
    int lane = t & 63, wid = t >> 6;
    int wm = wid >> 1, wn = wid & 1;
    int l31 = lane & 31, l7 = lane & 7, kg = lane >> 5;
    int arow = (wm * 32 + l31) * 128;
    int brow = (wn * 32 + l31) * 128;
    f32x16 acc;
#pragma unroll
    for (int e = 0; e < 16; ++e) acc[e] = 0.f;
    for (int it = 0; it < 8; ++it) {
        __syncthreads();
#pragma unroll
        for (int i = 0; i < 4; ++i) {
            int e4 = t + i * 256;
            int r = e4 >> 4, p4 = (e4 & 15) * 4;
            int chx = (((p4 >> 3) ^ (r & 7)) << 3) + (p4 & 7);
            uint2 hi, lo;
            float4 kv = *(const float4*)(kbase + (size_t)r * NPIX + it * 64 + p4);
            split4(kv, hi, lo);
            *(uint2*)&As[r * 128 + chx] = hi;
            *(uint2*)&As[r * 128 + 64 + chx] = lo;
            float4 vv = *(const float4*)(vbase + (size_t)r * NPIX + it * 64 + p4);
            split4(vv, hi, lo);
            *(uint2*)&Bs[r * 128 + chx] = hi;
            *(uint2*)&Bs[r * 128 + 64 + chx] = lo;
        }
        __syncthreads();
        short8v ah[4], al[4], bh[4], bl[4];
#pragma unroll
        for (int ks = 0; ks < 4; ++ks) {
            int ch = ((ks * 2 + kg) ^ l7) << 3;
            ah[ks] = *(const short8v*)&As[arow + ch];
            al[ks] = *(const short8v*)&As[arow + 64 + ch];
            bh[ks] = *(const short8v*)&Bs[brow + ch];
            bl[ks] = *(const short8v*)&Bs[brow + 64 + ch];
        }
#pragma unroll
        for (int ks = 0; ks < 4; ++ks) {
            acc = __builtin_amdgcn_mfma_f32_32x32x16_bf16(ah[ks], bh[ks], acc, 0, 0, 0);
            acc = __builtin_amdgcn_mfma_f32_32x32x16_bf16(al[ks], bh[ks], acc, 0, 0, 0);
            acc = __builtin_amdgcn_mfma_f32_32x32x16_bf16(ah[ks], bl[ks], acc, 0, 0, 0);
        }
    }
    float* srow = sraw + ((size_t)(b * 8 + h) * 64) * 64;
#pragma unroll
    for (int j = 0; j < 16; ++j) {
        int p = wm * 32 + (j & 3) + 8 * (j >> 2) + 4 * kg;
        atomicAdd(&srow[p * 64 + wn * 32 + l31], acc[j]);
    }
}

// ---------------- 5) T[b,o,hp] = (Wo[o,h*64:] . sraw[b,h,p,:]) / (8*ksum*qsum) --------
__global__ __launch_bounds__(256) void t_kernel(
    const float* __restrict__ sraw, const float* __restrict__ qsum_all,
    const float* __restrict__ ksum_all, const float* __restrict__ Wo, float* __restrict__ T) {
    int idx = blockIdx.x * 256 + threadIdx.x;
    int hp = idx & 511, o = (idx >> 9) & 63, b = idx >> 15;
    int h = hp >> 6, pp = hp & 63;
    const float* srow = sraw + (((size_t)b * 8 + h) * 64 + pp) * 64;
    const float* wrow = Wo + (size_t)o * 512 + h * 64;
    float acc = 0.f;
#pragma unroll
    for (int c = 0; c < 64; ++c) acc += wrow[c] * srow[c];
    float ks = ksum_all[b * 512 + hp];
    float qs = qsum_all[b * 512 + hp];
    T[idx] = acc / (8.f * ks * qs);
}

// ---------------- 6) GEMM2 via MFMA: out[b,o,px] = bo[o] + sum_hp T[o,hp]*expq[hp,px] --
// grid (64 pxtiles, 8 b). Per block: M=64 (o), N=64 (px), K=512 hp, split-bf16 3-term.
// B staged via register transpose: thread owns 1 px column x 16 hp (coalesced scalar loads).
__global__ __launch_bounds__(256) void gemm2_mfma_kernel(
    const float* __restrict__ qkv, const float* __restrict__ T_all,
    const float* __restrict__ bo, float* __restrict__ out) {
    __shared__ __align__(16) short lds[16384];  // As(T) 16KB | Bs(expq^T) 16KB
    short* As = lds;
    short* Bs = lds + 8192;
    int pix0 = blockIdx.x * 64, b = blockIdx.y;
    const float* Tb = T_all + (size_t)b * 64 * 512;
    const float* qb = qkv + (size_t)b * NROW * NPIX;
    int t = threadIdx.x;
    int lane = t & 63, wid = t >> 6;
    int wm = wid & 1, wn = wid >> 1;
    int l31 = lane & 31, l7 = lane & 7, kg = lane >> 5;
    int arow = (wm * 32 + l31) * 128;
    int brow = (wn * 32 + l31) * 128;
    int px0 = t & 63, hpq = (t >> 6) * 16;
    f32x16 acc;
#pragma unroll
    for (int e = 0; e < 16; ++e) acc[e] = 0.f;
    for (int it = 0; it < 8; ++it) {
        __syncthreads();
        // A: T tile [64 o][64 hp]
#pragma unroll
        for (int i = 0; i < 4; ++i) {
            int e4 = t + i * 256;
            int o = e4 >> 4, p4 = (e4 & 15) * 4;
            int chx = (((p4 >> 3) ^ (o & 7)) << 3) + (p4 & 7);
            float4 tv = *(const float4*)(Tb + (size_t)o * 512 + it * 64 + p4);
            uint2 hi, lo;
            split4(tv, hi, lo);
            *(uint2*)&As[o * 128 + chx] = hi;
            *(uint2*)&As[o * 128 + 64 + chx] = lo;
        }
        // B: expq^T — 16 coalesced scalar column loads, then quad packs
        float colv[16];
#pragma unroll
        for (int e = 0; e < 16; ++e)
            colv[e] = qb[(size_t)(it * 64 + hpq + e) * NPIX + pix0 + px0];
#pragma unroll
        for (int qd = 0; qd < 4; ++qd) {
            int hpl = hpq + qd * 4;
            float4 v4 = make_float4(colv[qd * 4], colv[qd * 4 + 1],
                                    colv[qd * 4 + 2], colv[qd * 4 + 3]);
            uint2 hi, lo;
            split4(v4, hi, lo);
            int chx = (((hpl >> 3) ^ (px0 & 7)) << 3) + (hpl & 7);
            *(uint2*)&Bs[px0 * 128 + chx] = hi;
            *(uint2*)&Bs[px0 * 128 + 64 + chx] = lo;
        }
        __syncthreads();
        short8v ah[4], al[4], bh[4], bl[4];
#pragma unroll
        for (int ks = 0; ks < 4; ++ks) {
            int ch = ((ks * 2 + kg) ^ l7) << 3;
            ah[ks] = *(const short8v*)&As[arow + ch];
            al[ks] = *(const short8v*)&As[arow + 64 + ch];
            bh[ks] = *(const short8v*)&Bs[brow + ch];
            bl[ks] = *(const short8v*)&Bs[brow + 64 + ch];
        }
#pragma unroll
        for (int ks = 0; ks < 4; ++ks) {
            acc = __builtin_amdgcn_mfma_f32_32x32x16_bf16(ah[ks], bh[ks], acc, 0, 0, 0);
            acc = __builtin_amdgcn_mfma_f32_32x32x16_bf16(al[ks], bh[ks], acc, 0, 0, 0);
            acc = __builtin_amdgcn_mfma_f32_32x32x16_bf16(ah[ks], bl[ks], acc, 0, 0, 0);
        }
    }
#pragma unroll
    for (int j = 0; j < 16; ++j) {
        int o = wm * 32 + (j & 3) + 8 * (j >> 2) + 4 * kg;
        out[((size_t)b * 64 + o) * NPIX + pix0 + wn * 32 + l31] = acc[j] + bo[o];
    }
}

// ---------------- workspace layout (floats) ----------------
#define OFF_SCALE 0                     // [8][64]          = 512
#define OFF_SHIFT 512                   // [8][64]          = 512
#define OFF_QSUM  1024                  // [8][512]         = 4096
#define OFF_KSUM  5120                  // [8][512]         = 4096
#define OFF_SRAW  9216                  // [8][8][64][64]   = 262144
#define OFF_T     271360                // [8][64][512]     = 262144
#define OFF_QKV   533504                // [8][1536][4096]  = 50331648
#define WS_FLOATS (533504 + 50331648)

extern "C" void kernel_launch(void* const* d_in, const int* in_sizes, int n_in,
                              void* d_out, int out_size, void* d_ws, size_t ws_size,
                              hipStream_t stream) {
    const float* x  = (const float*)d_in[0];
    const float* gg = (const float*)d_in[1];
    const float* gb = (const float*)d_in[2];
    const float* Wq = (const float*)d_in[3];
    const float* bq = (const float*)d_in[4];
    const float* Wk = (const float*)d_in[5];
    const float* bk = (const float*)d_in[6];
    const float* Wv = (const float*)d_in[7];
    const float* bv = (const float*)d_in[8];
    const float* Wo = (const float*)d_in[9];
    const float* bo = (const float*)d_in[10];
    float* out = (float*)d_out;
    float* ws = (float*)d_ws;
    if (ws_size < (size_t)WS_FLOATS * sizeof(float)) return;

    float* scale = ws + OFF_SCALE;
    float* shift = ws + OFF_SHIFT;
    float* qsum  = ws + OFF_QSUM;
    float* ksum  = ws + OFF_KSUM;
    float* sraw  = ws + OFF_SRAW;
    float* T     = ws + OFF_T;
    float* qkv   = ws + OFF_QKV;

    gn_zero_kernel<<<512, 256, 0, stream>>>(x, gg, gb, scale, shift, sraw);
    gemm1_mfma_kernel<<<dim3(32, 12, 8), 256, 0, stream>>>(x, scale, shift, Wq, bq, Wk, bk,
                                                           Wv, bv, qkv);
    rowsum_kernel<<<8192, 256, 0, stream>>>(qkv, qsum, ksum);
    s_accum_mfma_kernel<<<dim3(8, 8, 8), 256, 0, stream>>>(qkv, sraw);
    t_kernel<<<1024, 256, 0, stream>>>(sraw, qsum, ksum, Wo, T);
    gemm2_mfma_kernel<<<dim3(64, 8), 256, 0, stream>>>(qkv, T, bo, out);
}

// Round 8
// 193.298 us; speedup vs baseline: 1.7304x; 1.0034x over previous
//
#include <hip/hip_runtime.h>
#include <math.h>

#define BATCH 8
#define CH 64
#define NHEADS 8
#define NPIX 4096
#define QROWS 512

typedef __attribute__((ext_vector_type(8))) short short8v;
typedef __attribute__((ext_vector_type(16))) float f32x16;

// ---------------- reductions ----------------
__device__ inline float wave_sum(float v) {
#pragma unroll
    for (int off = 32; off; off >>= 1) v += __shfl_down(v, off, 64);
    return v;
}

// rne fp32 -> bf16 hi, and lo = bf16(f - hi)
__device__ inline void split_bf16(float f, short& h, short& l) {
    unsigned u = __float_as_uint(f);
    unsigned r = u + 0x7FFFu + ((u >> 16) & 1u);
    h = (short)(r >> 16);
    float hf = __uint_as_float(r & 0xFFFF0000u);
    float lf = f - hf;
    unsigned u2 = __float_as_uint(lf);
    unsigned r2 = u2 + 0x7FFFu + ((u2 >> 16) & 1u);
    l = (short)(r2 >> 16);
}

__device__ inline void split4(const float4 v, uint2& hi, uint2& lo) {
    short h0, h1, h2, h3, l0, l1, l2, l3;
    split_bf16(v.x, h0, l0); split_bf16(v.y, h1, l1);
    split_bf16(v.z, h2, l2); split_bf16(v.w, h3, l3);
    hi.x = (unsigned short)h0 | ((unsigned)(unsigned short)h1 << 16);
    hi.y = (unsigned short)h2 | ((unsigned)(unsigned short)h3 << 16);
    lo.x = (unsigned short)l0 | ((unsigned)(unsigned short)l1 << 16);
    lo.y = (unsigned short)l2 | ((unsigned)(unsigned short)l3 << 16);
}

// ---------------- 1) GroupNorm stats + zero (sraw+ksum) ----------------
// grid 516: blocks <256 do GN (b*32+g); blocks >=256 zero 266240 floats (sraw 262144 + ksum 4096).
__global__ __launch_bounds__(256) void gn_zero_kernel(
    const float* __restrict__ x, const float* __restrict__ gamma,
    const float* __restrict__ beta, float* __restrict__ scale, float* __restrict__ shift,
    float* __restrict__ zbase) {
    if (blockIdx.x >= 256) {
        ((float4*)zbase)[(blockIdx.x - 256) * 256 + threadIdx.x] =
            make_float4(0.f, 0.f, 0.f, 0.f);
        return;
    }
    int b = blockIdx.x >> 5, g = blockIdx.x & 31;
    const float4* p = (const float4*)(x + ((size_t)b * CH + 2 * g) * NPIX);
    float s = 0.f, ss = 0.f;
#pragma unroll
    for (int i = 0; i < 8; ++i) {
        float4 v = p[threadIdx.x + i * 256];
        s += v.x + v.y + v.z + v.w;
        ss += v.x * v.x + v.y * v.y + v.z * v.z + v.w * v.w;
    }
    s = wave_sum(s);
    ss = wave_sum(ss);
    __shared__ float rs[4], rss[4];
    int lane = threadIdx.x & 63, wv = threadIdx.x >> 6;
    if (lane == 0) { rs[wv] = s; rss[wv] = ss; }
    __syncthreads();
    if (threadIdx.x == 0) {
        s = rs[0] + rs[1] + rs[2] + rs[3];
        ss = rss[0] + rss[1] + rss[2] + rss[3];
        float mu = s * (1.f / 8192.f);
        float var = ss * (1.f / 8192.f) - mu * mu;
        float rstd = rsqrtf(var + 1e-6f);
#pragma unroll
        for (int cc = 0; cc < 2; ++cc) {
            int c = 2 * g + cc;
            float sc = rstd * gamma[c];
            scale[b * CH + c] = sc;
            shift[b * CH + c] = beta[c] - mu * sc;
        }
    }
}

// ---------------- 2) GEMM1-Q: expq[b,row,pix] = exp(Wq[row,:]@xn + bq)  (R7-proven path) ----
// grid (32 pxtiles, 4 rowtiles, 8 b). A=Wq, B=xn. qkv compact: [b][512 rows][4096 px].
__global__ __launch_bounds__(256) void gemm1_q_kernel(
    const float* __restrict__ x, const float* __restrict__ scale_all,
    const float* __restrict__ shift_all,
    const float* __restrict__ Wq, const float* __restrict__ bq,
    float* __restrict__ qkv) {
    __shared__ __align__(16) char lds[65536];
    short* As = (short*)lds;
    short* Bs = (short*)(lds + 32768);
    float* Bf = (float*)lds;

    int t = threadIdx.x;
    int b = blockIdx.z;
    int row0 = blockIdx.y * 128, pix0 = blockIdx.x * 128;

    float4 w4[8];
#pragma unroll
    for (int i = 0; i < 8; ++i) {
        int idx = t + i * 256;
        int r = idx >> 4, c4 = idx & 15;
        w4[i] = *(const float4*)(Wq + (size_t)(row0 + r) * 64 + c4 * 4);
    }
    const float* scale = scale_all + b * CH;
    const float* shift = shift_all + b * CH;
#pragma unroll
    for (int i = 0; i < 8; ++i) {
        int idx = t + i * 256;
        int c = idx >> 5, p4 = (idx & 31) * 4;
        float4 v = *(const float4*)(x + ((size_t)b * CH + c) * NPIX + pix0 + p4);
        float sc = scale[c], sh = shift[c];
        v.x = fmaf(v.x, sc, sh); v.y = fmaf(v.y, sc, sh);
        v.z = fmaf(v.z, sc, sh); v.w = fmaf(v.w, sc, sh);
        *(float4*)&Bf[c * 132 + p4] = v;
    }
    __syncthreads();
    int mypx = t & 127, chalf = t >> 7;
    float xv[32];
#pragma unroll
    for (int e = 0; e < 32; ++e) xv[e] = Bf[(chalf * 32 + e) * 132 + mypx];
    __syncthreads();
#pragma unroll
    for (int i = 0; i < 8; ++i) {
        int idx = t + i * 256;
        int r = idx >> 4, c4 = (idx & 15) * 4;
        uint2 hi, lo;
        split4(w4[i], hi, lo);
        int chh = ((c4 >> 3) ^ (r & 7));
        int chl = ((8 + (c4 >> 3)) ^ (r & 7));
        *(uint2*)&As[r * 128 + chh * 8 + (c4 & 7)] = hi;
        *(uint2*)&As[r * 128 + chl * 8 + (c4 & 7)] = lo;
    }
    {
        short h[32], l[32];
#pragma unroll
        for (int e = 0; e < 32; ++e) split_bf16(xv[e], h[e], l[e]);
#pragma unroll
        for (int w = 0; w < 4; ++w) {
            short8v hv, lv;
#pragma unroll
            for (int e = 0; e < 8; ++e) { hv[e] = h[w * 8 + e]; lv[e] = l[w * 8 + e]; }
            int chh = ((chalf * 4 + w) ^ (mypx & 7));
            int chl = ((8 + chalf * 4 + w) ^ (mypx & 7));
            *(short8v*)&Bs[mypx * 128 + chh * 8] = hv;
            *(short8v*)&Bs[mypx * 128 + chl * 8] = lv;
        }
    }
    __syncthreads();

    int lane = t & 63, wid = t >> 6;
    int wm = wid >> 1, wn = wid & 1;
    int l31 = lane & 31, l7 = lane & 7, kg = lane >> 5;
    int arow = wm * 64 + l31;
    int brow = wn * 64 + l31;
    f32x16 acc[2][2];
#pragma unroll
    for (int mt = 0; mt < 2; ++mt)
#pragma unroll
        for (int nt = 0; nt < 2; ++nt)
#pragma unroll
            for (int e = 0; e < 16; ++e) acc[mt][nt][e] = 0.f;
    const int ACH[12] = {0, 2, 4, 6, 8, 10, 12, 14, 0, 2, 4, 6};
    const int BCH[12] = {0, 2, 4, 6, 0, 2, 4, 6, 8, 10, 12, 14};
#pragma unroll
    for (int ks = 0; ks < 12; ++ks) {
        int ach = ACH[ks] + kg, bch = BCH[ks] + kg;
        short8v a0 = *(const short8v*)&As[arow * 128 + ((ach ^ l7) << 3)];
        short8v a1 = *(const short8v*)&As[(arow + 32) * 128 + ((ach ^ l7) << 3)];
        short8v b0 = *(const short8v*)&Bs[brow * 128 + ((bch ^ l7) << 3)];
        short8v b1 = *(const short8v*)&Bs[(brow + 32) * 128 + ((bch ^ l7) << 3)];
        acc[0][0] = __builtin_amdgcn_mfma_f32_32x32x16_bf16(a0, b0, acc[0][0], 0, 0, 0);
        acc[0][1] = __builtin_amdgcn_mfma_f32_32x32x16_bf16(a0, b1, acc[0][1], 0, 0, 0);
        acc[1][0] = __builtin_amdgcn_mfma_f32_32x32x16_bf16(a1, b0, acc[1][0], 0, 0, 0);
        acc[1][1] = __builtin_amdgcn_mfma_f32_32x32x16_bf16(a1, b1, acc[1][1], 0, 0, 0);
    }
#pragma unroll
    for (int mt = 0; mt < 2; ++mt) {
#pragma unroll
        for (int j = 0; j < 16; ++j) {
            int rl = wm * 64 + mt * 32 + (j & 3) + 8 * (j >> 2) + 4 * kg;
            float bi = bq[row0 + rl];
#pragma unroll
            for (int nt = 0; nt < 2; ++nt) {
                float val = __expf(acc[mt][nt][j] + bi);
                qkv[((size_t)b * QROWS + row0 + rl) * NPIX + pix0 + wn * 64 + nt * 32 + l31] = val;
            }
        }
    }
}

// ---------------- 3) fused KV: project k,v (SWAPPED operands) + ksum + k^T.v contraction ----
// grid (32 pxtiles, 4 kvtiles, 8 b). Swapped projection: A=xn (M=px), B=W (N=krow) ->
// D: col(l31)=krow, regs=px -- contraction-ready orientation. expk/v -> LDS (E,V) as
// quad-packed b64 in the chunk-XOR staging format; contraction D[p][c] += E.V^T over
// px=128 (3-term split-bf16), atomicAdd into sraw. k,v NEVER written to global.
// LDS 128KB: As(W)32K | Bs(xn)32K | Eh 32K | El 32K ; V overlays As/Bs after v-proj.
__global__ __launch_bounds__(256) void gemm_kv_fused_kernel(
    const float* __restrict__ x, const float* __restrict__ scale_all,
    const float* __restrict__ shift_all,
    const float* __restrict__ Wk, const float* __restrict__ bk,
    const float* __restrict__ Wv, const float* __restrict__ bv,
    float* __restrict__ sraw, float* __restrict__ ksum) {
    __shared__ __align__(16) char lds[131072];
    short* As = (short*)lds;
    short* Bs = (short*)(lds + 32768);
    short* Eh = (short*)(lds + 65536);
    short* El = (short*)(lds + 98304);
    short* Vh = (short*)lds;            // overlays As after v-projection done
    short* Vl = (short*)(lds + 32768);  // overlays Bs
    float* Bf = (float*)lds;

    int t = threadIdx.x;
    int b = blockIdx.z;
    int r = blockIdx.y;                 // kv tile: k rows [128r,128r+128), heads 2r,2r+1
    int pix0 = blockIdx.x * 128;

    // Wk -> regs
    float4 w4[8];
#pragma unroll
    for (int i = 0; i < 8; ++i) {
        int idx = t + i * 256;
        int rr = idx >> 4, c4 = idx & 15;
        w4[i] = *(const float4*)(Wk + (size_t)(r * 128 + rr) * 64 + c4 * 4);
    }
    // stage1: xn -> Bf (fp32)
    const float* scale = scale_all + b * CH;
    const float* shift = shift_all + b * CH;
#pragma unroll
    for (int i = 0; i < 8; ++i) {
        int idx = t + i * 256;
        int c = idx >> 5, p4 = (idx & 31) * 4;
        float4 v = *(const float4*)(x + ((size_t)b * CH + c) * NPIX + pix0 + p4);
        float sc = scale[c], sh = shift[c];
        v.x = fmaf(v.x, sc, sh); v.y = fmaf(v.y, sc, sh);
        v.z = fmaf(v.z, sc, sh); v.w = fmaf(v.w, sc, sh);
        *(float4*)&Bf[c * 132 + p4] = v;
    }
    __syncthreads();
    // stage2: transpose to regs
    int mypx = t & 127, chalf = t >> 7;
    float xv[32];
#pragma unroll
    for (int e = 0; e < 32; ++e) xv[e] = Bf[(chalf * 32 + e) * 132 + mypx];
    __syncthreads();
    // stage3a: Wk -> As ; stage3b: xn -> Bs
#pragma unroll
    for (int i = 0; i < 8; ++i) {
        int idx = t + i * 256;
        int rr = idx >> 4, c4 = (idx & 15) * 4;
        uint2 hi, lo;
        split4(w4[i], hi, lo);
        int chh = ((c4 >> 3) ^ (rr & 7));
        int chl = ((8 + (c4 >> 3)) ^ (rr & 7));
        *(uint2*)&As[rr * 128 + chh * 8 + (c4 & 7)] = hi;
        *(uint2*)&As[rr * 128 + chl * 8 + (c4 & 7)] = lo;
    }
    {
        short h[32], l[32];
#pragma unroll
        for (int e = 0; e < 32; ++e) split_bf16(xv[e], h[e], l[e]);
#pragma unroll
        for (int w = 0; w < 4; ++w) {
            short8v hv, lv;
#pragma unroll
            for (int e = 0; e < 8; ++e) { hv[e] = h[w * 8 + e]; lv[e] = l[w * 8 + e]; }
            int chh = ((chalf * 4 + w) ^ (mypx & 7));
            int chl = ((8 + chalf * 4 + w) ^ (mypx & 7));
            *(short8v*)&Bs[mypx * 128 + chh * 8] = hv;
            *(short8v*)&Bs[mypx * 128 + chl * 8] = lv;
        }
    }
    // prefetch Wv while k-phase runs
    float4 w4v[8];
#pragma unroll
    for (int i = 0; i < 8; ++i) {
        int idx = t + i * 256;
        int rr = idx >> 4, c4 = idx & 15;
        w4v[i] = *(const float4*)(Wv + (size_t)(r * 128 + rr) * 64 + c4 * 4);
    }
    __syncthreads();

    int lane = t & 63, wid = t >> 6;
    int wm = wid >> 1, wn = wid & 1;
    int l31 = lane & 31, l7 = lane & 7, kg = lane >> 5;
    int axrow = wm * 64 + l31;   // A = xn row (px)
    int bwrow = wn * 64 + l31;   // B = W row (krow)
    // terms: xh*wh, xl*wh, xh*wl
    const int XCH[12] = {0, 2, 4, 6, 8, 10, 12, 14, 0, 2, 4, 6};
    const int WCH[12] = {0, 2, 4, 6, 0, 2, 4, 6, 8, 10, 12, 14};

    f32x16 acc[2][2];
#pragma unroll
    for (int mt = 0; mt < 2; ++mt)
#pragma unroll
        for (int nt = 0; nt < 2; ++nt)
#pragma unroll
            for (int e = 0; e < 16; ++e) acc[mt][nt][e] = 0.f;
#pragma unroll
    for (int ks = 0; ks < 12; ++ks) {
        int xch = XCH[ks] + kg, wch = WCH[ks] + kg;
        short8v a0 = *(const short8v*)&Bs[axrow * 128 + ((xch ^ l7) << 3)];
        short8v a1 = *(const short8v*)&Bs[(axrow + 32) * 128 + ((xch ^ l7) << 3)];
        short8v b0 = *(const short8v*)&As[bwrow * 128 + ((wch ^ l7) << 3)];
        short8v b1 = *(const short8v*)&As[(bwrow + 32) * 128 + ((wch ^ l7) << 3)];
        acc[0][0] = __builtin_amdgcn_mfma_f32_32x32x16_bf16(a0, b0, acc[0][0], 0, 0, 0);
        acc[0][1] = __builtin_amdgcn_mfma_f32_32x32x16_bf16(a0, b1, acc[0][1], 0, 0, 0);
        acc[1][0] = __builtin_amdgcn_mfma_f32_32x32x16_bf16(a1, b0, acc[1][0], 0, 0, 0);
        acc[1][1] = __builtin_amdgcn_mfma_f32_32x32x16_bf16(a1, b1, acc[1][1], 0, 0, 0);
    }
    // epilogue k: D[px=wm*64+mt*32+(j&3)+8*(j>>2)+4kg][krow=wn*64+nt*32+l31]
    // exp, per-krow partial rowsum (lane-local over 32 px) + shfl_xor(32) + atomic,
    // quad-pack -> Eh/El with staging chunk-XOR (ch = wm*8+mt*4+g, slot +4kg).
#pragma unroll
    for (int nt = 0; nt < 2; ++nt) {
        int krow = wn * 64 + nt * 32 + l31;
        float bi = bk[r * 128 + krow];
        float part = 0.f;
#pragma unroll
        for (int mt = 0; mt < 2; ++mt) {
#pragma unroll
            for (int g = 0; g < 4; ++g) {
                float4 ev;
                ev.x = __expf(acc[mt][nt][g * 4 + 0] + bi);
                ev.y = __expf(acc[mt][nt][g * 4 + 1] + bi);
                ev.z = __expf(acc[mt][nt][g * 4 + 2] + bi);
                ev.w = __expf(acc[mt][nt][g * 4 + 3] + bi);
                part += ev.x + ev.y + ev.z + ev.w;
                uint2 hi, lo;
                split4(ev, hi, lo);
                int ch = wm * 8 + mt * 4 + g;
                int off = krow * 128 + ((ch ^ (krow & 7)) << 3) + 4 * kg;
                *(uint2*)&Eh[off] = hi;
                *(uint2*)&El[off] = lo;
            }
        }
        part += __shfl_xor(part, 32);
        if (kg == 0) atomicAdd(&ksum[b * 512 + r * 128 + krow], part);
    }
    __syncthreads();   // all As(Wk)/Bs reads done
    // stage Wv -> As
#pragma unroll
    for (int i = 0; i < 8; ++i) {
        int idx = t + i * 256;
        int rr = idx >> 4, c4 = (idx & 15) * 4;
        uint2 hi, lo;
        split4(w4v[i], hi, lo);
        int chh = ((c4 >> 3) ^ (rr & 7));
        int chl = ((8 + (c4 >> 3)) ^ (rr & 7));
        *(uint2*)&As[rr * 128 + chh * 8 + (c4 & 7)] = hi;
        *(uint2*)&As[rr * 128 + chl * 8 + (c4 & 7)] = lo;
    }
    __syncthreads();
    // v k-loop (same swapped form)
#pragma unroll
    for (int mt = 0; mt < 2; ++mt)
#pragma unroll
        for (int nt = 0; nt < 2; ++nt)
#pragma unroll
            for (int e = 0; e < 16; ++e) acc[mt][nt][e] = 0.f;
#pragma unroll
    for (int ks = 0; ks < 12; ++ks) {
        int xch = XCH[ks] + kg, wch = WCH[ks] + kg;
        short8v a0 = *(const short8v*)&Bs[axrow * 128 + ((xch ^ l7) << 3)];
        short8v a1 = *(const short8v*)&Bs[(axrow + 32) * 128 + ((xch ^ l7) << 3)];
        short8v b0 = *(const short8v*)&As[bwrow * 128 + ((wch ^ l7) << 3)];
        short8v b1 = *(const short8v*)&As[(bwrow + 32) * 128 + ((wch ^ l7) << 3)];
        acc[0][0] = __builtin_amdgcn_mfma_f32_32x32x16_bf16(a0, b0, acc[0][0], 0, 0, 0);
        acc[0][1] = __builtin_amdgcn_mfma_f32_32x32x16_bf16(a0, b1, acc[0][1], 0, 0, 0);
        acc[1][0] = __builtin_amdgcn_mfma_f32_32x32x16_bf16(a1, b0, acc[1][0], 0, 0, 0);
        acc[1][1] = __builtin_amdgcn_mfma_f32_32x32x16_bf16(a1, b1, acc[1][1], 0, 0, 0);
    }
    __syncthreads();   // all As(Wv)/Bs(xn) reads done -> V may overlay
    // epilogue v -> Vh/Vl (overlay As/Bs)
#pragma unroll
    for (int nt = 0; nt < 2; ++nt) {
        int vrow = wn * 64 + nt * 32 + l31;
        float bi = bv[r * 128 + vrow];
#pragma unroll
        for (int mt = 0; mt < 2; ++mt) {
#pragma unroll
            for (int g = 0; g < 4; ++g) {
                float4 vv;
                vv.x = acc[mt][nt][g * 4 + 0] + bi;
                vv.y = acc[mt][nt][g * 4 + 1] + bi;
                vv.z = acc[mt][nt][g * 4 + 2] + bi;
                vv.w = acc[mt][nt][g * 4 + 3] + bi;
                uint2 hi, lo;
                split4(vv, hi, lo);
                int ch = wm * 8 + mt * 4 + g;
                int off = vrow * 128 + ((ch ^ (vrow & 7)) << 3) + 4 * kg;
                *(uint2*)&Vh[off] = hi;
                *(uint2*)&Vl[off] = lo;
            }
        }
    }
    __syncthreads();
    // contraction: wave (hh = head-in-tile, pp = p-half). D[p][c] over K=128 px,
    // terms EhVh + ElVh + EhVl, 8 ksteps each, C in {0,1} -> 48 MFMA.
    int hh = wid & 1, pp = wid >> 1;
    int ar = (hh * 64 + pp * 32 + l31) * 128;
    int br0 = (hh * 64 + l31) * 128;
    int br1 = (hh * 64 + 32 + l31) * 128;
    f32x16 cacc[2];
#pragma unroll
    for (int C = 0; C < 2; ++C)
#pragma unroll
        for (int e = 0; e < 16; ++e) cacc[C][e] = 0.f;
#pragma unroll
    for (int s = 0; s < 8; ++s) {
        int ch = (((2 * s + kg) ^ l7) << 3);
        short8v a = *(const short8v*)&Eh[ar + ch];
        short8v b0 = *(const short8v*)&Vh[br0 + ch];
        short8v b1 = *(const short8v*)&Vh[br1 + ch];
        cacc[0] = __builtin_amdgcn_mfma_f32_32x32x16_bf16(a, b0, cacc[0], 0, 0, 0);
        cacc[1] = __builtin_amdgcn_mfma_f32_32x32x16_bf16(a, b1, cacc[1], 0, 0, 0);
    }
#pragma unroll
    for (int s = 0; s < 8; ++s) {
        int ch = (((2 * s + kg) ^ l7) << 3);
        short8v a = *(const short8v*)&El[ar + ch];
        short8v b0 = *(const short8v*)&Vh[br0 + ch];
        short8v b1 = *(const short8v*)&Vh[br1 + ch];
        cacc[0] = __builtin_amdgcn_mfma_f32_32x32x16_bf16(a, b0, cacc[0], 0, 0, 0);
        cacc[1] = __builtin_amdgcn_mfma_f32_32x32x16_bf16(a, b1, cacc[1], 0, 0, 0);
    }
#pragma unroll
    for (int s = 0; s < 8; ++s) {
        int ch = (((2 * s + kg) ^ l7) << 3);
        short8v a = *(const short8v*)&Eh[ar + ch];
        short8v b0 = *(const short8v*)&Vl[br0 + ch];
        short8v b1 = *(const short8v*)&Vl[br1 + ch];
        cacc[0] = __builtin_amdgcn_mfma_f32_32x32x16_bf16(a, b0, cacc[0], 0, 0, 0);
        cacc[1] = __builtin_amdgcn_mfma_f32_32x32x16_bf16(a, b1, cacc[1], 0, 0, 0);
    }
    // sraw atomics: D col(l31)=c, row(j,kg)=p
    int h = r * 2 + hh;
    float* sr = sraw + (((size_t)b * 8 + h) * 64) * 64;
#pragma unroll
    for (int C = 0; C < 2; ++C) {
#pragma unroll
        for (int j = 0; j < 16; ++j) {
            int p = pp * 32 + (j & 3) + 8 * (j >> 2) + 4 * kg;
            int c = C * 32 + l31;
            atomicAdd(&sr[p * 64 + c], cacc[C][j]);
        }
    }
}

// ---------------- 4) row sums of expq ----------------
__global__ __launch_bounds__(256) void rowsum_q_kernel(
    const float* __restrict__ qkv, float* __restrict__ qsum) {
    int b = blockIdx.x >> 9, row = blockIdx.x & 511;
    const float4* p = (const float4*)(qkv + ((size_t)b * QROWS + row) * NPIX);
    float s = 0.f;
#pragma unroll
    for (int i = 0; i < 4; ++i) {
        float4 v = p[threadIdx.x + i * 256];
        s += v.x + v.y + v.z + v.w;
    }
    s = wave_sum(s);
    __shared__ float rs[4];
    int lane = threadIdx.x & 63, wv = threadIdx.x >> 6;
    if (lane == 0) rs[wv] = s;
    __syncthreads();
    if (threadIdx.x == 0)
        qsum[b * 512 + row] = rs[0] + rs[1] + rs[2] + rs[3];
}

// ---------------- 5) T[b,o,hp] = (Wo[o,h*64:] . sraw[b,h,p,:]) / (8*ksum*qsum) --------
__global__ __launch_bounds__(256) void t_kernel(
    const float* __restrict__ sraw, const float* __restrict__ qsum_all,
    const float* __restrict__ ksum_all, const float* __restrict__ Wo, float* __restrict__ T) {
    int idx = blockIdx.x * 256 + threadIdx.x;
    int hp = idx & 511, o = (idx >> 9) & 63, b = idx >> 15;
    int h = hp >> 6, pp = hp & 63;
    const float* srow = sraw + (((size_t)b * 8 + h) * 64 + pp) * 64;
    const float* wrow = Wo + (size_t)o * 512 + h * 64;
    float acc = 0.f;
#pragma unroll
    for (int c = 0; c < 64; ++c) acc += wrow[c] * srow[c];
    float ks = ksum_all[b * 512 + hp];
    float qs = qsum_all[b * 512 + hp];
    T[idx] = acc / (8.f * ks * qs);
}

// ---------------- 6) GEMM2 via MFMA: out[b,o,px] = bo[o] + sum_hp T[o,hp]*expq[hp,px] --
__global__ __launch_bounds__(256) void gemm2_mfma_kernel(
    const float* __restrict__ qkv, const float* __restrict__ T_all,
    const float* __restrict__ bo, float* __restrict__ out) {
    __shared__ __align__(16) short lds[16384];
    short* As = lds;
    short* Bs = lds + 8192;
    int pix0 = blockIdx.x * 64, b = blockIdx.y;
    const float* Tb = T_all + (size_t)b * 64 * 512;
    const float* qb = qkv + (size_t)b * QROWS * NPIX;
    int t = threadIdx.x;
    int lane = t & 63, wid = t >> 6;
    int wm = wid & 1, wn = wid >> 1;
    int l31 = lane & 31, l7 = lane & 7, kg = lane >> 5;
    int arow = (wm * 32 + l31) * 128;
    int brow = (wn * 32 + l31) * 128;
    int px0 = t & 63, hpq = (t >> 6) * 16;
    f32x16 acc;
#pragma unroll
    for (int e = 0; e < 16; ++e) acc[e] = 0.f;
    for (int it = 0; it < 8; ++it) {
        __syncthreads();
#pragma unroll
        for (int i = 0; i < 4; ++i) {
            int e4 = t + i * 256;
            int o = e4 >> 4, p4 = (e4 & 15) * 4;
            int chx = (((p4 >> 3) ^ (o & 7)) << 3) + (p4 & 7);
            float4 tv = *(const float4*)(Tb + (size_t)o * 512 + it * 64 + p4);
            uint2 hi, lo;
            split4(tv, hi, lo);
            *(uint2*)&As[o * 128 + chx] = hi;
            *(uint2*)&As[o * 128 + 64 + chx] = lo;
        }
        float colv[16];
#pragma unroll
        for (int e = 0; e < 16; ++e)
            colv[e] = qb[(size_t)(it * 64 + hpq + e) * NPIX + pix0 + px0];
#pragma unroll
        for (int qd = 0; qd < 4; ++qd) {
            int hpl = hpq + qd * 4;
            float4 v4 = make_float4(colv[qd * 4], colv[qd * 4 + 1],
                                    colv[qd * 4 + 2], colv[qd * 4 + 3]);
            uint2 hi, lo;
            split4(v4, hi, lo);
            int chx = (((hpl >> 3) ^ (px0 & 7)) << 3) + (hpl & 7);
            *(uint2*)&Bs[px0 * 128 + chx] = hi;
            *(uint2*)&Bs[px0 * 128 + 64 + chx] = lo;
        }
        __syncthreads();
        short8v ah[4], al[4], bh[4], bl[4];
#pragma unroll
        for (int ks = 0; ks < 4; ++ks) {
            int ch = ((ks * 2 + kg) ^ l7) << 3;
            ah[ks] = *(const short8v*)&As[arow + ch];
            al[ks] = *(const short8v*)&As[arow + 64 + ch];
            bh[ks] = *(const short8v*)&Bs[brow + ch];
            bl[ks] = *(const short8v*)&Bs[brow + 64 + ch];
        }
#pragma unroll
        for (int ks = 0; ks < 4; ++ks) {
            acc = __builtin_amdgcn_mfma_f32_32x32x16_bf16(ah[ks], bh[ks], acc, 0, 0, 0);
            acc = __builtin_amdgcn_mfma_f32_32x32x16_bf16(al[ks], bh[ks], acc, 0, 0, 0);
            acc = __builtin_amdgcn_mfma_f32_32x32x16_bf16(ah[ks], bl[ks], acc, 0, 0, 0);
        }
    }
#pragma unroll
    for (int j = 0; j < 16; ++j) {
        int o = wm * 32 + (j & 3) + 8 * (j >> 2) + 4 * kg;
        out[((size_t)b * 64 + o) * NPIX + pix0 + wn * 32 + l31] = acc[j] + bo[o];
    }
}

// ---------------- workspace layout (floats) ----------------
#define OFF_SCALE 0                     // [8][64]          = 512
#define OFF_SHIFT 512                   // [8][64]          = 512
#define OFF_QSUM  1024                  // [8][512]         = 4096
#define OFF_SRAW  5120                  // [8][8][64][64]   = 262144
#define OFF_KSUM  267264                // [8][512]         = 4096   (adjacent to sraw: one zero range)
#define OFF_T     271360                // [8][64][512]     = 262144
#define OFF_QKV   533504                // [8][512][4096]   = 16777216 (expq only)
#define WS_FLOATS (533504 + 16777216)
// zero range [OFF_SRAW, OFF_KSUM+4096) = 266240 floats = 66560 float4 = 260 blocks * 256

extern "C" void kernel_launch(void* const* d_in, const int* in_sizes, int n_in,
                              void* d_out, int out_size, void* d_ws, size_t ws_size,
                              hipStream_t stream) {
    const float* x  = (const float*)d_in[0];
    const float* gg = (const float*)d_in[1];
    const float* gb = (const float*)d_in[2];
    const float* Wq = (const float*)d_in[3];
    const float* bq = (const float*)d_in[4];
    const float* Wk = (const float*)d_in[5];
    const float* bk = (const float*)d_in[6];
    const float* Wv = (const float*)d_in[7];
    const float* bv = (const float*)d_in[8];
    const float* Wo = (const float*)d_in[9];
    const float* bo = (const float*)d_in[10];
    float* out = (float*)d_out;
    float* ws = (float*)d_ws;
    if (ws_size < (size_t)WS_FLOATS * sizeof(float)) return;

    float* scale = ws + OFF_SCALE;
    float* shift = ws + OFF_SHIFT;
    float* qsum  = ws + OFF_QSUM;
    float* sraw  = ws + OFF_SRAW;
    float* ksum  = ws + OFF_KSUM;
    float* T     = ws + OFF_T;
    float* qkv   = ws + OFF_QKV;

    gn_zero_kernel<<<516, 256, 0, stream>>>(x, gg, gb, scale, shift, sraw);
    gemm1_q_kernel<<<dim3(32, 4, 8), 256, 0, stream>>>(x, scale, shift, Wq, bq, qkv);
    gemm_kv_fused_kernel<<<dim3(32, 4, 8), 256, 0, stream>>>(x, scale, shift, Wk, bk, Wv, bv,
                                                             sraw, ksum);
    rowsum_q_kernel<<<4096, 256, 0, stream>>>(qkv, qsum);
    t_kernel<<<1024, 256, 0, stream>>>(sraw, qsum, ksum, Wo, T);
    gemm2_mfma_kernel<<<dim3(64, 8), 256, 0, stream>>>(qkv, T, bo, out);
}